// Round 3
// baseline (180.497 us; speedup 1.0000x reference)
//
#include <hip/hip_runtime.h>

// Problem constants (from reference): N=8, H=512, W=512, K=1, NF=100000, D=8
#define NN 8
#define HH 512
#define WW 512
#define DD 8

constexpr int HW   = HH * WW;        // 262144 (pow2)
constexpr int NPIX = NN * HW;        // 2,097,152
constexpr int BLK  = 256;            // 4 independent waves per block
constexpr int FST  = 33;             // 32 faces + 1 pad chunk (odd stride)

typedef float v4f __attribute__((ext_vector_type(4)));

// Each face row in attr is 24 floats = 96 B = 6 x float4 "chunks".
// Wave-local cooperative gather (consecutive lanes -> consecutive chunks of
// the SAME face, ~1.5 line-requests/face), two-batch LDS transpose
// (12.7 KB/block -> 8 blocks/CU), NO __syncthreads anywhere.
//
// Round-3 fix: round 2 compiled to 32 VGPRs — too few to keep 6 gather
// loads in flight, so the compiler rotated 2-3 buffers and serialized the
// pipeline (occupancy rose, time didn't). Here all 6 loads are issued into
// an explicit L[6] and pinned with sched_barrier(0) before any ds_write:
// the wave holds a true 6-deep vmcnt pipeline (writes drain at vmcnt(5..3),
// batch-A blend/stores overlap the batch-B load tail).
__global__ __launch_bounds__(256, 8) void interp_mlp(
    const int*   __restrict__ p2f,   // [N*H*W] packed face index, -1 = empty
    const float* __restrict__ bary,  // [N*H*W, 3]
    const float* __restrict__ attr,  // [N*NF, 3, D] -> 6 float4 per face
    float*       __restrict__ out)   // [N, D+1, H, W]
{
    __shared__ v4f chunks[BLK / 64][6 * FST];   // 4 x 198 x 16 B = 12,672 B

    const int t    = threadIdx.x;
    const int lane = t & 63;
    const int wv   = t >> 6;
    const int i    = blockIdx.x * BLK + t;      // this thread's pixel
    const int wb   = blockIdx.x * BLK + wv * 64; // wave's first pixel

    // --- cooperative bary load: 192 consecutive floats per wave in 3 fully
    //     dense coalesced rounds (6 line-requests vs 12 for strided) ---
    const float* bw = bary + (size_t)wb * 3;
    const float bv0 = __builtin_nontemporal_load(bw + 0 * 64 + lane);
    const float bv1 = __builtin_nontemporal_load(bw + 1 * 64 + lane);
    const float bv2 = __builtin_nontemporal_load(bw + 2 * 64 + lane);

    // --- per-pixel face id ---
    const int  f     = __builtin_nontemporal_load(p2f + i);
    const bool valid = f >= 0;
    const int  fc    = valid ? f : 0;

    // redistribute bary: element 3*lane+k lives in round (3l+k)>>6, lane (3l+k)&63
    auto bget = [&](int idx) {
        const int s = idx & 63;
        const float a = __shfl(bv0, s, 64);
        const float b = __shfl(bv1, s, 64);
        const float c = __shfl(bv2, s, 64);
        const int r = idx >> 6;
        return r == 0 ? a : (r == 1 ? b : c);
    };
    float b0 = bget(3 * lane + 0);
    float b1 = bget(3 * lane + 1);
    float b2 = bget(3 * lane + 2);
    if (!valid) { b0 = 0.0f; b1 = 0.0f; b2 = 0.0f; }

    const v4f* ap = (const v4f*)attr;
    v4f* ch = chunks[wv];                       // this wave's private region

    // --- issue ALL 6 gather loads up-front (6-deep MLP per wave) ---
    int wadr[6];
    v4f L[6];
    #pragma unroll
    for (int j = 0; j < 6; ++j) {
        const int w  = j * 64 + lane;           // consecutive lanes -> consecutive (p,c)
        const int p  = w / 6;                   // pixel within wave [0,64)
        const int c  = w - p * 6;               // chunk within face [0,6)
        const int ff = __shfl(fc, p, 64);       // face id from owning lane
        wadr[j] = c * FST + (p & 31);           // slot reused by both batches
        L[j] = ap[(size_t)ff * 6 + c];
    }
    // Pin: no load may be sunk below this point -> all 6 stay in flight.
    __builtin_amdgcn_sched_barrier(0);

    // --- planar output [N, D+1, H, W], coalesced per plane ---
    const int n   = i >> 18;                    // i / HW
    const int pix = i & (HW - 1);               // i % HW
    float* ob = out + (size_t)n * (DD + 1) * HW + pix;

    auto blendStore = [&](int slot) {
        const v4f x0 = ch[0 * FST + slot];      // vert0 ch0-3
        const v4f x1 = ch[1 * FST + slot];      // vert0 ch4-7
        const v4f y0 = ch[2 * FST + slot];
        const v4f y1 = ch[3 * FST + slot];
        const v4f z0 = ch[4 * FST + slot];
        const v4f z1 = ch[5 * FST + slot];
        const v4f lo = b0 * x0 + b1 * y0 + b2 * z0;   // ch0-3
        const v4f hi = b0 * x1 + b1 * y1 + b2 * z1;   // ch4-7
        __builtin_nontemporal_store(lo.x, ob + 0 * (size_t)HW);
        __builtin_nontemporal_store(lo.y, ob + 1 * (size_t)HW);
        __builtin_nontemporal_store(lo.z, ob + 2 * (size_t)HW);
        __builtin_nontemporal_store(lo.w, ob + 3 * (size_t)HW);
        __builtin_nontemporal_store(hi.x, ob + 4 * (size_t)HW);
        __builtin_nontemporal_store(hi.y, ob + 5 * (size_t)HW);
        __builtin_nontemporal_store(hi.z, ob + 6 * (size_t)HW);
        __builtin_nontemporal_store(hi.w, ob + 7 * (size_t)HW);
        __builtin_nontemporal_store(valid ? 1.0f : 0.0f, ob + 8 * (size_t)HW);
    };

    // --- batch A: rounds 0-2 complete pixels [0,32) ---
    #pragma unroll
    for (int j = 0; j < 3; ++j) ch[wadr[j]] = L[j];   // vmcnt(5..3)
    if (lane < 32) blendStore(lane);                  // overlaps L[3..5] tail

    // --- batch B: rounds 3-5 complete pixels [32,64), reusing the slots ---
    #pragma unroll
    for (int j = 3; j < 6; ++j) ch[wadr[j]] = L[j];   // vmcnt(2..0)
    if (lane >= 32) blendStore(lane - 32);
}

extern "C" void kernel_launch(void* const* d_in, const int* in_sizes, int n_in,
                              void* d_out, int out_size, void* d_ws, size_t ws_size,
                              hipStream_t stream) {
    const int*   p2f  = (const int*)d_in[0];
    const float* bary = (const float*)d_in[1];
    const float* attr = (const float*)d_in[2];
    float*       out  = (float*)d_out;

    const int grid = NPIX / BLK;               // 8192 blocks
    interp_mlp<<<grid, BLK, 0, stream>>>(p2f, bary, attr, out);
}